// Round 1
// baseline (480.611 us; speedup 1.0000x reference)
//
#include <hip/hip_runtime.h>

// BoxFilter r=8 (k=17), fused separable pass over [8,32,512,512] fp32.
// One block = one (image, 128-row strip). Horizontal 17-tap from an LDS row
// buffer; vertical pass as a running sum over a 17-row LDS ring buffer.
// Zero padding matches the reference (edges attenuate, scale = 1/289).

#define HH 512
#define WW 512
#define RR 8
#define KK 17
#define CH 128              // output rows per block
#define TPB 256             // threads per block; each owns 2 columns
#define TILES (HH / CH)     // 4 strips per image

__global__ __launch_bounds__(TPB, 4) void box_fused(const float* __restrict__ x,
                                                    float* __restrict__ out) {
    __shared__ __align__(16) float raw[WW + 2 * RR];   // current row + halo
    __shared__ __align__(16) float ring[KK][WW];       // last 17 horizontal rows

    const int tid = threadIdx.x;
    const int img = blockIdx.x / TILES;
    const int h0  = (blockIdx.x % TILES) * CH;
    const float* xi = x + (size_t)img * HH * WW;
    float*       oi = out + (size_t)img * HH * WW;
    const int c0 = tid * 2;

    // Zero the horizontal halo once (cols <0 and >=W map to 0).
    if (tid < RR) { raw[tid] = 0.0f; raw[WW + RR + tid] = 0.0f; }
    // Zero the vertical ring (rows before the strip contribute 0).
    for (int i = tid; i < KK * WW; i += TPB) (&ring[0][0])[i] = 0.0f;
    __syncthreads();

    float vs0 = 0.0f, vs1 = 0.0f;
    int s = 0;
    const float inv_k2 = 1.0f / (float)(KK * KK);

    for (int idx = 0; idx < CH + 2 * RR; ++idx) {
        const int  rr    = h0 - RR + idx;
        const bool inrow = (rr >= 0) && (rr < HH);

        if (inrow) {
            const float2 v = ((const float2*)(xi + (size_t)rr * WW))[tid];
            ((float2*)(raw + RR))[tid] = v;
        }
        __syncthreads();

        float hs0 = 0.0f, hs1 = 0.0f;
        if (inrow) {
            // raw positions c0 .. c0+17 cover both columns' 17-tap windows.
            float2 a[9];
#pragma unroll
            for (int j = 0; j < 9; ++j)
                a[j] = *(const float2*)(raw + c0 + 2 * j);
            float ssum = 0.0f;
#pragma unroll
            for (int j = 0; j < 9; ++j) ssum += a[j].x + a[j].y;
            hs0 = ssum - a[8].y;   // cols c0-8 .. c0+8
            hs1 = ssum - a[0].x;   // cols c0-7 .. c0+9
        }

        // Vertical running sum: add new row, subtract row from 17 ago.
        // Ring slot (s, c0) is touched only by this thread -> no extra sync.
        float2 old = *(float2*)&ring[s][c0];
        vs0 += hs0 - old.x;
        vs1 += hs1 - old.y;
        float2 nw; nw.x = hs0; nw.y = hs1;
        *(float2*)&ring[s][c0] = nw;
        if (++s == KK) s = 0;

        if (idx >= 2 * RR) {            // window full: emit row rr - RR
            const int ro = rr - RR;     // in [h0, h0+CH)
            float2 o;
            o.x = vs0 * inv_k2;
            o.y = vs1 * inv_k2;
            ((float2*)(oi + (size_t)ro * WW))[tid] = o;
        }
        __syncthreads();                // protect raw before next row's load
    }
}

extern "C" void kernel_launch(void* const* d_in, const int* in_sizes, int n_in,
                              void* d_out, int out_size, void* d_ws, size_t ws_size,
                              hipStream_t stream) {
    const float* x   = (const float*)d_in[0];
    float*       out = (float*)d_out;
    const int nImg = in_sizes[0] / (HH * WW);   // 8*32 = 256 images
    dim3 grid(nImg * TILES), block(TPB);
    box_fused<<<grid, block, 0, stream>>>(x, out);
}

// Round 2
// 444.301 us; speedup vs baseline: 1.0817x; 1.0817x over previous
//
#include <hip/hip_runtime.h>

// BoxFilter r=8 (k=17), fused separable pass over [8,32,512,512] fp32.
// One block = one (image, ~171-row strip), grid = 256*3 = 768 = exactly
// 3 blocks/CU resident in a single round.
// Pipeline: 4-row chunks, double-buffered LDS row staging, register prefetch
// two chunks ahead (cp.async-style), ONE barrier per chunk.
// Horizontal 17-tap from LDS rows; vertical = running sum over a 17-row
// LDS ring. Zero padding matches reference; scale 1/289.

#define WW   512
#define HH   512
#define RR   8
#define KK   17
#define TPB  256
#define RPC  4                  // rows per chunk
#define RAWP (WW + 2 * RR)      // 528 floats per staged row
#define NSTRIP 3
#define NCHUNK 47               // ceil((171 + 16) / 4) row-slots = 188

__global__ __launch_bounds__(TPB, 3)
void box_fused(const float* __restrict__ x, float* __restrict__ out) {
    __shared__ __align__(16) float raw[2][RPC][RAWP];  // double-buffered rows
    __shared__ __align__(16) float ring[KK][WW];       // 17-row horiz history

    const int tid   = threadIdx.x;
    const int img   = blockIdx.x / NSTRIP;
    const int strip = blockIdx.x % NSTRIP;
    const int h0 = (strip * HH) / NSTRIP;          // 0, 170, 341
    const int h1 = ((strip + 1) * HH) / NSTRIP;    // 170, 341, 512
    const int CH = h1 - h0;                        // 170 or 171

    const float* xi = x + (size_t)img * HH * WW;
    float*       oi = out + (size_t)img * HH * WW;

    // staging decode: 2 float4 loads/thread cover 4 rows x 512 floats
    const int r0 = tid >> 7,              c4_0 = (tid & 127) * 4;
    const int r1 = (tid + TPB) >> 7,      c4_1 = (tid & 127) * 4; // f1=tid+256: row +2, same col
    // note: (tid+256)&127 == tid&127, (tid+256)>>7 == r0+2

    // zero horizontal halos of both buffers (never rewritten) + ring
    if (tid < 128) {
        int b = tid >> 6, rem = tid & 63;
        int r = rem >> 4, side = (rem >> 3) & 1, c = rem & 7;
        raw[b][r][side ? (WW + RR + c) : c] = 0.0f;
    }
    for (int i = tid; i < KK * WW; i += TPB) (&ring[0][0])[i] = 0.0f;

    // ---- prologue: stage chunk 0, prefetch chunk 1 ----
    float4 p0, p1;
    {
        int rr0 = h0 - RR + r0, rr1 = h0 - RR + r1;
        p0 = make_float4(0.f, 0.f, 0.f, 0.f);
        p1 = make_float4(0.f, 0.f, 0.f, 0.f);
        if (rr0 >= 0 && rr0 < HH) p0 = *(const float4*)(xi + (size_t)rr0 * WW + c4_0);
        if (rr1 >= 0 && rr1 < HH) p1 = *(const float4*)(xi + (size_t)rr1 * WW + c4_1);
    }
    *(float4*)&raw[0][r0][RR + c4_0] = p0;
    *(float4*)&raw[0][r1][RR + c4_1] = p1;
    {
        int rr0 = h0 - RR + RPC + r0, rr1 = h0 - RR + RPC + r1;
        p0 = make_float4(0.f, 0.f, 0.f, 0.f);
        p1 = make_float4(0.f, 0.f, 0.f, 0.f);
        if (rr0 >= 0 && rr0 < HH) p0 = *(const float4*)(xi + (size_t)rr0 * WW + c4_0);
        if (rr1 >= 0 && rr1 < HH) p1 = *(const float4*)(xi + (size_t)rr1 * WW + c4_1);
    }
    __syncthreads();

    const int   c0  = tid * 2;
    const float inv = 1.0f / (float)(KK * KK);
    float vs0 = 0.f, vs1 = 0.f;
    int s = 0;

    for (int ch = 0; ch < NCHUNK; ++ch) {
        const int cur = ch & 1, nxt = cur ^ 1;

        // write prefetched chunk ch+1 into the other buffer (vmcnt waits here)
        if (ch + 1 < NCHUNK) {
            *(float4*)&raw[nxt][r0][RR + c4_0] = p0;
            *(float4*)&raw[nxt][r1][RR + c4_1] = p1;
        }
        // issue prefetch of chunk ch+2 (in flight through the whole compute)
        if (ch + 2 < NCHUNK) {
            int rr0 = h0 - RR + (ch + 2) * RPC + r0;
            int rr1 = h0 - RR + (ch + 2) * RPC + r1;
            p0 = make_float4(0.f, 0.f, 0.f, 0.f);
            p1 = make_float4(0.f, 0.f, 0.f, 0.f);
            if (rr0 >= 0 && rr0 < HH) p0 = *(const float4*)(xi + (size_t)rr0 * WW + c4_0);
            if (rr1 >= 0 && rr1 < HH) p1 = *(const float4*)(xi + (size_t)rr1 * WW + c4_1);
        }

        // compute 4 rows out of buffer `cur`
#pragma unroll
        for (int j = 0; j < RPC; ++j) {
            const int g = ch * RPC + j;                 // row idx within strip+halo
            const float* rb = &raw[cur][j][0];
            float2 a[9];
#pragma unroll
            for (int q = 0; q < 9; ++q) a[q] = *(const float2*)(rb + c0 + 2 * q);
            float ssum = 0.f;
#pragma unroll
            for (int q = 0; q < 9; ++q) ssum += a[q].x + a[q].y;
            const float hs0 = ssum - a[8].y;            // cols c0-8 .. c0+8
            const float hs1 = ssum - a[0].x;            // cols c0-7 .. c0+9

            float2 old = *(float2*)&ring[s][c0];
            vs0 += hs0 - old.x;
            vs1 += hs1 - old.y;
            *(float2*)&ring[s][c0] = make_float2(hs0, hs1);
            if (++s == KK) s = 0;

            if (g >= 2 * RR && g < CH + 2 * RR) {
                float2 o = make_float2(vs0 * inv, vs1 * inv);
                ((float2*)(oi + (size_t)(h0 + g - 2 * RR) * WW))[tid] = o;
            }
        }
        __syncthreads();   // buf `nxt` staged + everyone done reading `cur`
    }
}

extern "C" void kernel_launch(void* const* d_in, const int* in_sizes, int n_in,
                              void* d_out, int out_size, void* d_ws, size_t ws_size,
                              hipStream_t stream) {
    const float* x   = (const float*)d_in[0];
    float*       out = (float*)d_out;
    const int nImg = in_sizes[0] / (HH * WW);   // 8*32 = 256 images
    dim3 grid(nImg * NSTRIP), block(TPB);
    box_fused<<<grid, block, 0, stream>>>(x, out);
}